// Round 10
// baseline (161.153 us; speedup 1.0000x reference)
//
#include <hip/hip_runtime.h>
#include <hip/hip_bf16.h>

#define HH 512
#define WW 512
#define CIN 256
#define COUT 256
#define NPTS 65536
#define PW 514
#define NPIX (PW * PW)
#define NKT 72                      // K tiles of 32; 36 B pair-stages of 64 ci

typedef __bf16 bf16x8 __attribute__((ext_vector_type(8)));
typedef float f32x16 __attribute__((ext_vector_type(16)));
typedef unsigned short us8 __attribute__((ext_vector_type(8)));

static __device__ __forceinline__ unsigned short f2bf(float f) {
  unsigned u = __builtin_bit_cast(unsigned, f);
  unsigned r = u + 0x7fffu + ((u >> 16) & 1u);
  return (unsigned short)(r >> 16);
}

static __device__ __forceinline__ void gload16(const void* g, void* l) {
  __builtin_amdgcn_global_load_lds(
      (const __attribute__((address_space(1))) unsigned int*)g,
      (__attribute__((address_space(3))) unsigned int*)l, 16, 0, 0);
}

// A layout (verified r2-r9): i = kt*8192 + o ; r = o>>5 (co),
// cp = (o>>3)&3, j = o&7, logical chunk c = cp ^ ((r>>1)&3),
// k = kt*32 + c*8 + j (k = t*256+ci). Linear 16KB DMA -> swizzled LDS tile.
__global__ __launch_bounds__(256) void prep_weight(const float* __restrict__ w,
                                                   unsigned short* __restrict__ A) {
  int i = blockIdx.x * 256 + threadIdx.x;       // 72*8192 = 589824 total
  int kt = i >> 13;
  int o  = i & 8191;
  int r  = o >> 5;
  int cp = (o >> 3) & 3;
  int j  = o & 7;
  int c  = cp ^ ((r >> 1) & 3);
  int k  = kt * 32 + c * 8 + j;
  int t  = k >> 8;
  int ci = k & 255;
  A[i] = f2bf(__builtin_nontemporal_load(&w[r * 2304 + ci * 9 + t]));
}

// Zero the border ring of the padded (514x514) bf16 feature image.
__global__ __launch_bounds__(256) void border_zero(unsigned short* __restrict__ Ft) {
  int g = blockIdx.x * 256 + threadIdx.x;
  if (g >= 2052 * 32) return;
  int p = g >> 5, c = g & 31;
  int py, px;
  if (p < 514)        { py = 0;        px = p; }
  else if (p < 1028)  { py = 513;      px = p - 514; }
  else if (p < 1540)  { py = p - 1027; px = 0; }
  else                { py = p - 1539; px = 513; }
  *(us8*)&Ft[((size_t)py * PW + px) * 256 + c * 8] = (us8){0, 0, 0, 0, 0, 0, 0, 0};
}

// Ft[((y+1)*514 + (x+1))*256 + ci] = bf16(feature[ci][y][x])
// f32 reads NONTEMPORAL (r9, verified −12 µs): keep the 256 MB stream out of
// L2/L3 so Ft stays resident for the gemm's random gathers.
__global__ __launch_bounds__(256) void transpose_feat(const float* __restrict__ f,
                                                      unsigned short* __restrict__ Ft) {
  __shared__ unsigned short lds[64 * 264];
  int pix0 = blockIdx.x * 64;
  int y = pix0 >> 9, x0 = pix0 & 511;
  int tid = threadIdx.x;
  int p = tid & 63;
  int cb = tid >> 6;
  const float* src = f + pix0 + p;
  for (int c8 = 0; c8 < 8; ++c8) {
    us8 v;
#pragma unroll
    for (int j = 0; j < 8; ++j) {
      int ci = cb * 64 + c8 * 8 + j;
      v[j] = f2bf(__builtin_nontemporal_load(&src[ci * 262144]));
    }
    *(us8*)&lds[p * 264 + cb * 64 + c8 * 8] = v;
  }
  __syncthreads();
  int cic = tid & 31;
  int pr = tid >> 5;
  for (int g = 0; g < 8; ++g) {
    int p2 = pr + g * 8;
    us8 v = *(const us8*)&lds[p2 * 264 + cic * 8];
    *(us8*)&Ft[((size_t)((y + 1) * PW + x0 + 1 + p2)) * 256 + cic * 8] = v;
  }
}

// 256x256xK gather-GEMM. r8 buffers/ledger (A x3 staged t+2, B-pair x3
// staged q+2, vmcnt(6) once per tile) + m201-style two-phase split per
// k32-tile: {ds subtile; stage; barrier; lgkm(0); MFMA x8; barrier} x2,
// with the counted vmcnt folded into phase B's closing barrier.
__global__ __launch_bounds__(512, 2) void gemm_gather(
    const unsigned short* __restrict__ A,     // prep'd, swizzle baked in
    const unsigned short* __restrict__ Ft,    // [514*514][256] bf16 padded
    const int* __restrict__ hidx,
    const int* __restrict__ widx,
    float* __restrict__ out) {
  __shared__ unsigned short lds[73728];       // A: 3*8192 @0, B: 3*16384 @24576
  unsigned short* ldsB = lds + 24576;

  int tid = threadIdx.x;
  int lane = tid & 63, wv = tid >> 6;
  int wm = wv & 1, wn = wv >> 1;
  int n0 = blockIdx.x << 8;

  // B gather (verified r8): pass P covers cols [P*64, P*64+64); thread =
  // pixel col P*64+(tid>>3), phys chunk tid&7 holds logical (tid&7)^(col&7);
  // each pixel's 8 lanes read one contiguous 128B run.
  int pxc = tid >> 3;
  int lcB = (tid & 7) ^ (pxc & 7);
  const unsigned short *FtP0, *FtP1, *FtP2, *FtP3;
  {
    FtP0 = Ft + (long)(hidx[n0 + pxc] * PW + widx[n0 + pxc]) * 256 + lcB * 8;
    FtP1 = Ft + (long)(hidx[n0 + 64 + pxc] * PW + widx[n0 + 64 + pxc]) * 256 + lcB * 8;
    FtP2 = Ft + (long)(hidx[n0 + 128 + pxc] * PW + widx[n0 + 128 + pxc]) * 256 + lcB * 8;
    FtP3 = Ft + (long)(hidx[n0 + 192 + pxc] * PW + widx[n0 + 192 + pxc]) * 256 + lcB * 8;
  }

#define STAGE_A(t_, ab_)                                                      \
  do {                                                                        \
    const unsigned short* g_ = A + (size_t)(t_) * 8192 + tid * 8;             \
    unsigned short* l_ = lds + (ab_) * 8192 + tid * 8;                        \
    gload16(g_, l_);                                                          \
    gload16(g_ + 4096, l_ + 4096);                                            \
  } while (0)

// Pair q_: tap = q_>>2, ci0 = (q_&3)*64. 4 gloads; 128B/pixel contiguous.
#define STAGE_BP(q_, bb_)                                                     \
  do {                                                                        \
    int tap_ = (q_) >> 2;                                                     \
    long off_ = (long)((tap_ / 3) * PW + (tap_ - (tap_ / 3) * 3)) * 256 +     \
                ((q_) & 3) * 64;                                              \
    unsigned short* l_ = ldsB + (bb_) * 16384 + tid * 8;                      \
    gload16(FtP0 + off_, l_);                                                 \
    gload16(FtP1 + off_, l_ + 4096);                                         \
    gload16(FtP2 + off_, l_ + 8192);                                          \
    gload16(FtP3 + off_, l_ + 12288);                                         \
  } while (0)

#define LDA(dst, ab_, kg_, mt_)                                               \
  do {                                                                        \
    int r_ = wm * 128 + (mt_) * 32 + (lane & 31);                             \
    int c_ = ((kg_) * 2 + (lane >> 5)) ^ ((r_ >> 1) & 3);                     \
    dst = *(const bf16x8*)&lds[(ab_) * 8192 + r_ * 32 + c_ * 8];              \
  } while (0)

// B LDS: [col][chunk]: offset = col*64 + phys*8; phys = logical ^ (col&7).
// Tile parity s_ selects logical chunks s_*4..s_*4+3.
#define LDB(dst, bb_, s_, kg_, nt_)                                           \
  do {                                                                        \
    int col_ = wn * 64 + (nt_) * 32 + (lane & 31);                            \
    int ph_ = ((s_) * 4 + (kg_) * 2 + (lane >> 5)) ^ (col_ & 7);              \
    dst = *(const bf16x8*)&ldsB[(bb_) * 16384 + col_ * 64 + ph_ * 8];         \
  } while (0)

#define MF(x_, y_, z_) __builtin_amdgcn_mfma_f32_32x32x16_bf16(x_, y_, z_, 0, 0, 0)

#define SYNC_LGKM()                                                           \
  do {                                                                        \
    __builtin_amdgcn_s_barrier();                                             \
    asm volatile("s_waitcnt lgkmcnt(0)" ::: "memory");                        \
    __builtin_amdgcn_sched_barrier(0);                                        \
  } while (0)

// Two-phase k32-tile. Phase A: m-half 0 (mt 0,1) + all 4 B frags; Phase B:
// m-half 1 (mt 2,3) reusing B frags. vmcnt(6) before phase B's closing
// barrier = r8's per-tile ledger point (wait BEFORE barrier — r6 rule).
#define TILE(ab_, bb_, s_, STGA, STGB)                                        \
  do {                                                                        \
    bf16x8 a0, a1, a2, a3, b0, b1, b2, b3;                                    \
    LDA(a0, ab_, 0, 0); LDA(a1, ab_, 0, 1);                                   \
    LDA(a2, ab_, 1, 0); LDA(a3, ab_, 1, 1);                                   \
    LDB(b0, bb_, s_, 0, 0); LDB(b1, bb_, s_, 0, 1);                           \
    LDB(b2, bb_, s_, 1, 0); LDB(b3, bb_, s_, 1, 1);                           \
    STGA;                                                                     \
    SYNC_LGKM();                                                              \
    __builtin_amdgcn_s_setprio(1);                                            \
    acc[0][0] = MF(a0, b0, acc[0][0]); acc[0][1] = MF(a0, b1, acc[0][1]);     \
    acc[1][0] = MF(a1, b0, acc[1][0]); acc[1][1] = MF(a1, b1, acc[1][1]);     \
    acc[0][0] = MF(a2, b2, acc[0][0]); acc[0][1] = MF(a2, b3, acc[0][1]);     \
    acc[1][0] = MF(a3, b2, acc[1][0]); acc[1][1] = MF(a3, b3, acc[1][1]);     \
    __builtin_amdgcn_s_setprio(0);                                            \
    __builtin_amdgcn_s_barrier();                                             \
    LDA(a0, ab_, 0, 2); LDA(a1, ab_, 0, 3);                                   \
    LDA(a2, ab_, 1, 2); LDA(a3, ab_, 1, 3);                                   \
    STGB;                                                                     \
    SYNC_LGKM();                                                              \
    __builtin_amdgcn_s_setprio(1);                                            \
    acc[2][0] = MF(a0, b0, acc[2][0]); acc[2][1] = MF(a0, b1, acc[2][1]);     \
    acc[3][0] = MF(a1, b0, acc[3][0]); acc[3][1] = MF(a1, b1, acc[3][1]);     \
    acc[2][0] = MF(a2, b2, acc[2][0]); acc[2][1] = MF(a2, b3, acc[2][1]);     \
    acc[3][0] = MF(a3, b2, acc[3][0]); acc[3][1] = MF(a3, b3, acc[3][1]);     \
    __builtin_amdgcn_s_setprio(0);                                            \
    asm volatile("s_waitcnt vmcnt(6)" ::: "memory");                          \
    __builtin_amdgcn_s_barrier();                                             \
  } while (0)

  f32x16 acc[4][2];
#pragma unroll
  for (int mt = 0; mt < 4; ++mt)
#pragma unroll
    for (int nt = 0; nt < 2; ++nt)
      acc[mt][nt] = (f32x16)(0.f);

  // Prologue (r8 ledger order): BP(0), A(0), A(1), BP(1) -> 12 loads;
  // drain to 6 => A(0)+BP(0) resident for tile 0.
  STAGE_BP(0, 0);
  STAGE_A(0, 0);
  STAGE_A(1, 1);
  STAGE_BP(1, 1);
  asm volatile("s_waitcnt vmcnt(6)" ::: "memory");
  __builtin_amdgcn_s_barrier();

  // Steady state (ledger verified r8): uniform vmcnt(6) at every tile end.
  // Even tile t=2q: phase A stages A(t+2), phase B stages BP(q+2).
  // Odd tile: phase A stages A(t+3). Tail clamps target dead buffers.
  for (int P3 = 0; P3 < 12; ++P3) {
#pragma unroll
    for (int v = 0; v < 3; ++v) {
      int q = P3 * 3 + v;
      int t = 2 * q;
      TILE((2 * v) % 3, v, 0,
           STAGE_A((t + 2 < NKT ? t + 2 : NKT - 1), (2 * v + 2) % 3),
           STAGE_BP((q + 2 < 36 ? q + 2 : 35), (v + 2) % 3));
      TILE((2 * v + 1) % 3, v, 1,
           STAGE_A((t + 3 < NKT ? t + 3 : NKT - 1), (2 * v) % 3),
           (void)0);
    }
  }

#undef STAGE_A
#undef STAGE_BP
#undef LDA
#undef LDB
#undef MF
#undef SYNC_LGKM
#undef TILE

  // Epilogue (verified): col = lane&31, row = (r&3)+8*(r>>2)+4*(lane>>5).
  // Nontemporal stores (r9): output is a pure stream, keep it out of L3.
  int colb = n0 + wn * 64 + (lane & 31);
  int rb = wm * 128 + ((lane >> 5) << 2);
#pragma unroll
  for (int mt = 0; mt < 4; ++mt)
#pragma unroll
    for (int nt = 0; nt < 2; ++nt)
#pragma unroll
      for (int r = 0; r < 16; ++r) {
        int row = rb + mt * 32 + (r & 3) + ((r >> 2) << 3);
        __builtin_nontemporal_store(acc[mt][nt][r],
                                    &out[(size_t)row * NPTS + colb + nt * 32]);
      }
}

// Safety-net path if workspace is too small: direct conv, fp32.
__global__ __launch_bounds__(256) void naive_conv(const float* __restrict__ f,
                                                  const float* __restrict__ w,
                                                  const int* __restrict__ hi,
                                                  const int* __restrict__ wi,
                                                  float* __restrict__ out) {
  int idx = blockIdx.x * 256 + threadIdx.x;
  int n = idx & (NPTS - 1);
  int co = idx >> 16;
  int bh = hi[n] - 1;
  int bw = wi[n] - 1;
  float acc = 0.f;
  for (int ci = 0; ci < CIN; ++ci) {
    const float* fc = f + (size_t)ci * 262144;
    const float* wc = w + (size_t)co * 2304 + ci * 9;
#pragma unroll
    for (int t = 0; t < 9; ++t) {
      int y = bh + t / 3, x = bw + t % 3;
      float v = (y >= 0 && y < 512 && x >= 0 && x < 512) ? fc[y * 512 + x] : 0.f;
      acc += wc[t] * v;
    }
  }
  out[(size_t)co * NPTS + n] = acc;
}

extern "C" void kernel_launch(void* const* d_in, const int* in_sizes, int n_in,
                              void* d_out, int out_size, void* d_ws, size_t ws_size,
                              hipStream_t stream) {
  const float* feature = (const float*)d_in[0];
  const float* weight  = (const float*)d_in[1];
  const int* hidx      = (const int*)d_in[2];
  const int* widx      = (const int*)d_in[3];
  float* out           = (float*)d_out;

  const size_t FT_OFF = 2ull * 1024 * 1024;
  const size_t FT_BYTES = (size_t)NPIX * 256 * 2;   // ~135 MiB
  const size_t NEED = FT_OFF + FT_BYTES;

  if (ws_size >= NEED) {
    unsigned short* Abf = (unsigned short*)d_ws;    // 1.125 MiB
    unsigned short* Ft = (unsigned short*)((char*)d_ws + FT_OFF);
    prep_weight<<<(NKT * 8192) / 256, 256, 0, stream>>>(weight, Abf);
    border_zero<<<(2052 * 32 + 255) / 256, 256, 0, stream>>>(Ft);
    transpose_feat<<<262144 / 64, 256, 0, stream>>>(feature, Ft);
    gemm_gather<<<NPTS / 256, 512, 0, stream>>>(Abf, Ft, hidx, widx, out);
  } else {
    naive_conv<<<(COUT * NPTS) / 256, 256, 0, stream>>>(feature, weight, hidx, widx, out);
  }
}